// Round 5
// baseline (78.338 us; speedup 1.0000x reference)
//
#include <hip/hip_runtime.h>

#define VOCAB 30522
#define SEQ 512
#define NQ 4                       // vocab quarters per row
#define QENT 7632                  // vocab entries per quarter (last covers 7626)
#define QWORDS (QENT / 2)          // 3816 packed uint32 words (2 x uint16 counts)

typedef float f32x2 __attribute__((ext_vector_type(2)));

__global__ __launch_bounds__(256) void bow_row_kernel(const int* __restrict__ ids,
                                                      float* __restrict__ out) {
    __shared__ unsigned int hist[QWORDS];   // 15264 B -> 8 blocks/CU (thread-limited)
    __shared__ int s_cut;

    const int b   = blockIdx.x;    // one block per row
    const int tid = threadIdx.x;

    if (tid == 0) s_cut = SEQ;

    // Issue the row's token loads (512 tokens, 2/thread); zero the quarter-0
    // histogram under the load latency shadow.
    const int t0 = ids[(size_t)b * SEQ + tid];
    const int t1 = ids[(size_t)b * SEQ + tid + 256];

    for (int i = tid; i < QWORDS; i += 256) hist[i] = 0u;
    __syncthreads();

    // First-pad cutoff: token t counts iff t < min index of any pad token.
    if (t0 == 0) atomicMin(&s_cut, tid);
    if (t1 == 0) atomicMin(&s_cut, tid + 256);
    __syncthreads();

    const int  cut = s_cut;
    const bool v0  = tid < cut;
    const bool v1  = tid + 256 < cut;

    float* orow = out + (size_t)b * VOCAB;

    for (int q = 0; q < NQ; ++q) {
        const int lo = q * QENT;

        // Scatter this quarter's tokens. uint16 halves never carry (<=512/row).
        if (v0) {
            const int r = t0 - lo;
            if ((unsigned)r < (unsigned)QENT)
                atomicAdd(&hist[r >> 1], 1u << ((r & 1) << 4));
        }
        if (v1) {
            const int r = t1 - lo;
            if ((unsigned)r < (unsigned)QENT)
                atomicAdd(&hist[r >> 1], 1u << ((r & 1) << 4));
        }
        __syncthreads();

        // Stream the quarter out (nontemporal, write-once buffer) and fold the
        // re-zero into the same pass. Base is always 8B-aligned.
        const int nw = (q == NQ - 1) ? (VOCAB - (NQ - 1) * QENT) / 2 : QWORDS; // 3813 last
        float* obase = orow + lo;
        for (int i = tid; i < nw; i += 256) {
            const unsigned int w = hist[i];
            hist[i] = 0u;          // re-zero for next quarter in the same pass
            f32x2 f;
            f.x = (float)(w & 0xFFFFu);
            f.y = (float)(w >> 16);
            __builtin_nontemporal_store(f, reinterpret_cast<f32x2*>(obase + 2 * i));
        }

        if (q < NQ - 1) __syncthreads();   // zero visible before next scatter
    }
}

extern "C" void kernel_launch(void* const* d_in, const int* in_sizes, int n_in,
                              void* d_out, int out_size, void* d_ws, size_t ws_size,
                              hipStream_t stream) {
    const int* ids = (const int*)d_in[0];
    float* out     = (float*)d_out;
    const int B    = in_sizes[0] / SEQ;   // 2048

    bow_row_kernel<<<B, 256, 0, stream>>>(ids, out);
}

// Round 6
// 38.528 us; speedup vs baseline: 2.0333x; 2.0333x over previous
//
#include <hip/hip_runtime.h>

#define VOCAB 30522
#define SEQ 512
#define NQ 4                       // vocab quarters per row
#define QENT 7632                  // vocab entries per quarter (last covers 7626)
#define QWORDS (QENT / 2)          // 3816 packed uint32 words (2 x uint16 counts)

__global__ __launch_bounds__(256) void bow_row_kernel(const int* __restrict__ ids,
                                                      float* __restrict__ out) {
    __shared__ unsigned int hist[QWORDS];   // 15264 B -> 8 blocks/CU (thread-limited)
    __shared__ int s_cut;

    const int b   = blockIdx.x;    // one block per row
    const int tid = threadIdx.x;

    if (tid == 0) s_cut = SEQ;

    // Issue the row's token loads (512 tokens, 2/thread); zero the quarter-0
    // histogram under the load latency shadow.
    const int t0 = ids[(size_t)b * SEQ + tid];
    const int t1 = ids[(size_t)b * SEQ + tid + 256];

    for (int i = tid; i < QWORDS; i += 256) hist[i] = 0u;
    __syncthreads();

    // First-pad cutoff: token t counts iff t < min index of any pad token.
    if (t0 == 0) atomicMin(&s_cut, tid);
    if (t1 == 0) atomicMin(&s_cut, tid + 256);
    __syncthreads();

    const int  cut = s_cut;
    const bool v0  = tid < cut;
    const bool v1  = tid + 256 < cut;

    float* orow = out + (size_t)b * VOCAB;

    for (int q = 0; q < NQ; ++q) {
        const int lo = q * QENT;

        // Scatter this quarter's tokens. uint16 halves never carry (<=512/row).
        if (v0) {
            const int r = t0 - lo;
            if ((unsigned)r < (unsigned)QENT)
                atomicAdd(&hist[r >> 1], 1u << ((r & 1) << 4));
        }
        if (v1) {
            const int r = t1 - lo;
            if ((unsigned)r < (unsigned)QENT)
                atomicAdd(&hist[r >> 1], 1u << ((r & 1) << 4));
        }
        __syncthreads();

        // Stream the quarter out (regular stores — NT was a 2x regression, R5)
        // and fold the re-zero into the same pass. Base is always 8B-aligned.
        const int nw = (q == NQ - 1) ? (VOCAB - (NQ - 1) * QENT) / 2 : QWORDS; // 3813 last
        float* obase = orow + lo;
        for (int i = tid; i < nw; i += 256) {
            const unsigned int w = hist[i];
            hist[i] = 0u;          // re-zero for next quarter in the same pass
            float2 f = make_float2((float)(w & 0xFFFFu), (float)(w >> 16));
            *reinterpret_cast<float2*>(obase + 2 * i) = f;
        }

        if (q < NQ - 1) __syncthreads();   // zero visible before next scatter
    }
}

extern "C" void kernel_launch(void* const* d_in, const int* in_sizes, int n_in,
                              void* d_out, int out_size, void* d_ws, size_t ws_size,
                              hipStream_t stream) {
    const int* ids = (const int*)d_in[0];
    float* out     = (float*)d_out;
    const int B    = in_sizes[0] / SEQ;   // 2048

    bow_row_kernel<<<B, 256, 0, stream>>>(ids, out);
}